// Round 13
// baseline (160.595 us; speedup 1.0000x reference)
//
#include <hip/hip_runtime.h>
#include <hip/hip_bf16.h>
#include <stdint.h>

typedef __attribute__((ext_vector_type(8))) __bf16 bf16x8;
typedef __attribute__((ext_vector_type(8))) unsigned short u16x8;
typedef __attribute__((ext_vector_type(4))) float f32x4;
typedef __hip_bfloat16 bf16;

#define GLDS(g, l) __builtin_amdgcn_global_load_lds( \
    (const __attribute__((address_space(1))) void*)(g), \
    (__attribute__((address_space(3))) void*)(l), 16, 0, 0)

#define SCALE_Q 0.18033688f   // 0.125 * log2(e): softmax runs in exp2 domain
#define MFIX 12.0f            // fixed softmax max (log2 domain)

// ---------------- workspace layout (bytes) ----------------
#define OFF_XB     ((size_t)0)          // 4096*1024 bf16 = 8388608  (reused as attnb)
#define OFF_WQKVB  ((size_t)8388608)    // 3072*1024 bf16 (free during attn: pbuf/sb live here)
#define OFF_PBUF   ((size_t)8388608)    // 8*32*4096 bf16 = 2 MB (z=1 partial O)
#define OFF_SB0    ((size_t)10485760)   // 8*32*64 f32 = 64 KB
#define OFF_SB1    ((size_t)10551296)   // 64 KB
#define OFF_WOB    ((size_t)14680064)   // 1024*1024 bf16 = 2097152
#define OFF_QB     ((size_t)16777216)   // 32*2048*64 bf16 = 8388608
#define OFF_KB     ((size_t)25165824)
#define OFF_VTB    ((size_t)33554432)
#define OFF_CS     ((size_t)41943040)   // 2048*32 f32 = 262144
#define OFF_SN     ((size_t)42205184)

static __device__ __forceinline__ float b2f(unsigned short u) {
    union { unsigned u32; float f; } c; c.u32 = (unsigned)u << 16; return c.f;
}

// ---------------- fp32 -> bf16 conversion + RoPE table (region 5) ----------------
__global__ void prep_kernel(const float* __restrict__ x, const float* __restrict__ wq,
                            const float* __restrict__ wk, const float* __restrict__ wv,
                            const float* __restrict__ wo,
                            bf16* __restrict__ xb, bf16* __restrict__ wqkvb,
                            bf16* __restrict__ wob,
                            const int* __restrict__ pos, const void* __restrict__ theta_p,
                            float* __restrict__ cst, float* __restrict__ snt)
{
    const int region = blockIdx.y;
    if (region == 5) {                      // RoPE cos/sin table: [s][i], i = d/2
        if (blockIdx.x >= 256) return;
        const int t = blockIdx.x * 256 + threadIdx.x;   // 2048*32 = 65536
        const int s = t >> 5, i = t & 31;
        const int ti = ((const int*)theta_p)[0];
        const float theta = (ti > 0 && ti < 100000000) ? (float)ti : ((const float*)theta_p)[0];
        const float fr = expf(-(float)i * (1.0f / 32.0f) * logf(theta));
        const float ang = (float)pos[s] * fr;
        cst[t] = cosf(ang);
        snt[t] = sinf(ang);
        return;
    }
    const float* src;
    bf16* dst;
    int count;
    switch (region) {
        case 0:  src = x;  dst = xb;              count = 4096 * 1024; break;
        case 1:  src = wq; dst = wqkvb;           count = 1024 * 1024; break;
        case 2:  src = wk; dst = wqkvb + 1048576; count = 1024 * 1024; break;
        case 3:  src = wv; dst = wqkvb + 2097152; count = 1024 * 1024; break;
        default: src = wo; dst = wob;             count = 1024 * 1024; break;
    }
    const int i = (blockIdx.x * 256 + threadIdx.x) * 4;
    if (i >= count) return;
    const float4 v = *(const float4*)(src + i);
    union { bf16 h[4]; short4 s4; } u;
    u.h[0] = __float2bfloat16(v.x);
    u.h[1] = __float2bfloat16(v.y);
    u.h[2] = __float2bfloat16(v.z);
    u.h[3] = __float2bfloat16(v.w);
    *(short4*)(dst + i) = u.s4;
}

// ---------------- GEMM: C[M,N] = A[M,K] * B[N,K]^T, bf16 in, fp32 acc ----------------
template<int MODE, int BM>
__global__ __launch_bounds__(256) void gemm_bt(
    const bf16* __restrict__ A, const bf16* __restrict__ B,
    const int K, const int N,
    float* __restrict__ outf,
    bf16* __restrict__ qb, bf16* __restrict__ kb, bf16* __restrict__ vtb,
    const float* __restrict__ cst, const float* __restrict__ snt)
{
    constexpr int NF = BM / 32;
    __shared__ __align__(16) bf16 Asl[BM * 64];
    __shared__ __align__(16) bf16 Bsl[128 * 64];
    const int tid = threadIdx.x;
    const int wave = tid >> 6, lane = tid & 63;
    const int lr = lane & 15, lk = lane >> 4;

    // bijective XCD swizzle
    const int nwg = gridDim.x * gridDim.y;
    const int flat = blockIdx.y * gridDim.x + blockIdx.x;
    const int wg = (flat & 7) * (nwg >> 3) + (flat >> 3);
    const int m0 = (wg % gridDim.x) * BM;
    const int n0 = (wg / gridDim.x) * 128;

    const int wm = (wave >> 1) * (BM / 2);
    const int wn = (wave & 1) * 64;
    const int srow = tid >> 3, sseg = tid & 7;
    const int swel = (sseg ^ (srow & 7)) * 8;    // pre-swizzled element offset in row

    f32x4 acc[NF][4] = {};

    const bf16* aRow = A + (size_t)(m0 + srow) * K + swel;
    const bf16* bRow = B + (size_t)(n0 + srow) * K + swel;
    char* lA = (char*)Asl + tid * 16;
    char* lB = (char*)Bsl + tid * 16;
    const size_t rowK32 = (size_t)32 * K;

    for (int k0 = 0; k0 < K; k0 += 64) {
#pragma unroll
        for (int g = 0; g < NF; ++g)
            GLDS(aRow + k0 + g * rowK32, lA + g * 4096);
#pragma unroll
        for (int g = 0; g < 4; ++g)
            GLDS(bRow + k0 + g * rowK32, lB + g * 4096);
        __syncthreads();
#pragma unroll
        for (int kk = 0; kk < 2; ++kk) {
            const int s = kk * 4 + lk;           // 16B segment for this fragment
            bf16x8 af[NF], bfr[4];
#pragma unroll
            for (int i = 0; i < NF; ++i) {
                const int R = wm + i * 16 + lr;
                af[i] = *(const bf16x8*)((const char*)Asl + R * 128 + (((s) ^ (R & 7)) << 4));
            }
#pragma unroll
            for (int j = 0; j < 4; ++j) {
                const int R = wn + j * 16 + lr;
                bfr[j] = *(const bf16x8*)((const char*)Bsl + R * 128 + (((s) ^ (R & 7)) << 4));
            }
#pragma unroll
            for (int i = 0; i < NF; ++i)
#pragma unroll
                for (int j = 0; j < 4; ++j)
                    acc[i][j] = __builtin_amdgcn_mfma_f32_16x16x32_bf16(af[i], bfr[j], acc[i][j], 0, 0, 0);
        }
        __syncthreads();
    }

    if constexpr (MODE == 1) {
#pragma unroll
        for (int i = 0; i < NF; ++i)
#pragma unroll
            for (int j = 0; j < 4; ++j)
#pragma unroll
                for (int r = 0; r < 4; ++r) {
                    const int row = m0 + wm + i * 16 + lk * 4 + r;
                    const int col = n0 + wn + j * 16 + lr;
                    outf[(size_t)row * N + col] = acc[i][j][r];
                }
    } else {
        const int matn = n0 >> 10;   // 0=Q 1=K 2=V, uniform per block
#pragma unroll
        for (int i = 0; i < NF; ++i)
#pragma unroll
            for (int j = 0; j < 4; ++j)
#pragma unroll
                for (int r = 0; r < 4; ++r) {
                    const int row = m0 + wm + i * 16 + lk * 4 + r;
                    const int col = n0 + wn + j * 16 + lr;
                    float v = acc[i][j][r];
                    float p = __shfl_xor(v, 1);        // RoPE pair partner
                    const int e = col & 1023;
                    const int h = e >> 6;
                    const int dd = e & 63;
                    const int b = row >> 11;
                    const int s = row & 2047;
                    const size_t bhi = (size_t)(b * 16 + h);
                    if (matn == 2) {
                        vtb[(bhi * 64 + dd) * 2048 + s] = __float2bfloat16(v);
                    } else {
                        const float cs = cst[s * 32 + (dd >> 1)];
                        const float sn = snt[s * 32 + (dd >> 1)];
                        const float rv = (dd & 1) ? (p * sn + v * cs) : (v * cs - p * sn);
                        if (matn == 0)
                            qb[(bhi * 2048 + s) * 64 + dd] = __float2bfloat16(rv * SCALE_Q);
                        else
                            kb[(bhi * 2048 + s) * 64 + dd] = __float2bfloat16(rv);
                    }
                }
    }
}

// ---------------- causal flash attention, k-split for long strips ----------------
// grid (24, 32). xi<16: pair (xi, 31-xi); for xi<8 the B strip only covers
// kt in [0,h) (h = ceil((tB+1)/2)) and writes an UNNORMALIZED bf16 partial
// (into attnb slot) + row sums sb0. xi in [16,24): x=xi-16<8, B strip only,
// kt in [h,tB], partial into pbuf + sb1. Fixed-max softmax makes partials
// pure sums. A strip of split pairs is complete in z=0 (tA<8<=h).
__global__ __launch_bounds__(256) void attn_kernel(
    const bf16* __restrict__ qb, const bf16* __restrict__ kb,
    const bf16* __restrict__ vtb, bf16* __restrict__ attnb,
    bf16* __restrict__ pbuf, float* __restrict__ sb0, float* __restrict__ sb1)
{
    __shared__ __align__(16) bf16 Kl[2][64 * 64];
    __shared__ __align__(16) bf16 Vl[2][64 * 64];
    __shared__ __align__(16) bf16 Pl[4][2][16][72];   // [wave][strip][q][k], 144B rows
    const int tid = threadIdx.x;
    const int wave = tid >> 6, lane = tid & 63;
    const int lr = lane & 15, lk = lane >> 4;
    const int xi = blockIdx.x;
    const int bh = blockIdx.y;

    int tA, tB, ktBeg, ktEnd;
    bool hasA, partB, z1;
    if (xi < 16) {
        tA = xi; tB = 31 - xi;
        const int hk = (tB + 2) >> 1;      // ceil((tB+1)/2)
        z1 = false; hasA = true;
        if (xi < 8) { partB = true;  ktBeg = 0; ktEnd = hk - 1; }
        else        { partB = false; ktBeg = 0; ktEnd = tB; }
    } else {
        const int x = xi - 16;
        tA = -1; tB = 31 - x;
        const int hk = (tB + 2) >> 1;
        z1 = true; hasA = false; partB = true;
        ktBeg = hk; ktEnd = tB;
    }
    const int qA = (hasA ? tA : 0) * 64 + wave * 16;
    const int qB = tB * 64 + wave * 16;

    const bf16* Qp = qb + (size_t)bh * 2048 * 64;
    const bf16* Kp = kb + (size_t)bh * 2048 * 64;
    const bf16* Vp = vtb + (size_t)bh * 64 * 2048;

    const int srow = tid >> 3;
    const int sseg = tid & 7;
    const int sw16 = (sseg ^ (srow & 7)) * 16;
    const char* kg = (const char*)Kp + (size_t)srow * 128 + sw16;
    const char* vg = (const char*)Vp + (size_t)srow * 4096 + sw16;

#define STAGE(kt_, c_) do {                                              \
        const char* kgt = kg + (size_t)(kt_) * 8192;                     \
        GLDS(kgt,              &Kl[c_][0] + tid * 8);                    \
        GLDS(kgt + 32 * 128,   &Kl[c_][0] + 2048 + tid * 8);             \
        const char* vgt = vg + (size_t)(kt_) * 128;                      \
        GLDS(vgt,              &Vl[c_][0] + tid * 8);                    \
        GLDS(vgt + 32 * 4096,  &Vl[c_][0] + 2048 + tid * 8);             \
    } while (0)

    bf16x8 qfA[2], qfB[2];
#pragma unroll
    for (int ks = 0; ks < 2; ++ks) {
        qfA[ks] = *(const bf16x8*)(Qp + (qA + lr) * 64 + ks * 32 + lk * 8);
        qfB[ks] = *(const bf16x8*)(Qp + (qB + lr) * 64 + ks * 32 + lk * 8);
    }

    float sA = 0.f, sB = 0.f;
    f32x4 oA[4] = {}, oB[4] = {};

    STAGE(ktBeg, ktBeg & 1);

    const int xoff = (lr & 7) * 8;   // K/V swizzle: row&7 == lr&7 for rows j*16+lr

    for (int kt = ktBeg; kt <= ktEnd; ++kt) {
        const int c = kt & 1;
        const int kv0 = kt * 64;
        const bool doA = hasA && (kt <= tA);
        if (kt < ktEnd) {
            STAGE(kt + 1, c ^ 1);
            asm volatile("s_waitcnt vmcnt(4)" ::: "memory");  // kt landed; kt+1 in flight
        } else {
            asm volatile("s_waitcnt vmcnt(0)" ::: "memory");
        }
        __builtin_amdgcn_s_barrier();
        __builtin_amdgcn_sched_barrier(0);
        const bf16* Kc = &Kl[c][0];
        const bf16* Vc = &Vl[c][0];

        // ---- QK^T (swapped): scX[j][r] = P^T[k = j*16+lk*4+r][q = lr] ----
        f32x4 scB[4] = {}, scA[4] = {};
#pragma unroll
        for (int ks = 0; ks < 2; ++ks) {
            bf16x8 kf[4];
#pragma unroll
            for (int j = 0; j < 4; ++j)
                kf[j] = *(const bf16x8*)(Kc + (j * 16 + lr) * 64 + ((ks * 32 + lk * 8) ^ xoff));
            __builtin_amdgcn_s_setprio(1);
#pragma unroll
            for (int j = 0; j < 4; ++j)
                scB[j] = __builtin_amdgcn_mfma_f32_16x16x32_bf16(kf[j], qfB[ks], scB[j], 0, 0, 0);
            if (doA) {
#pragma unroll
                for (int j = 0; j < 4; ++j)
                    scA[j] = __builtin_amdgcn_mfma_f32_16x16x32_bf16(kf[j], qfA[ks], scA[j], 0, 0, 0);
            }
            __builtin_amdgcn_s_setprio(0);
        }

        // vf hoisted once per visit; loads overlap the softmax below
        bf16x8 vf[2][4];
#pragma unroll
        for (int ks = 0; ks < 2; ++ks)
#pragma unroll
            for (int j = 0; j < 4; ++j)
                vf[ks][j] = *(const bf16x8*)(Vc + (j * 16 + lr) * 64 + ((ks * 32 + lk * 8) ^ xoff));

        // ---- fixed-max softmax: P = exp2(sc - MFIX); branchless, lane-local ----
        auto smx = [&](f32x4* sc, float& ssum, int qX, bool diag, int st) {
            if (diag) {
#pragma unroll
                for (int j = 0; j < 4; ++j)
#pragma unroll
                    for (int r = 0; r < 4; ++r)
                        if (kv0 + j * 16 + lk * 4 + r > qX + lr) sc[j][r] = -1e30f;
            }
            float l0 = 0.f, l1 = 0.f, l2 = 0.f, l3 = 0.f;
#pragma unroll
            for (int j = 0; j < 4; ++j) {
                float pv[4];
                pv[0] = exp2f(sc[j][0] - MFIX);
                pv[1] = exp2f(sc[j][1] - MFIX);
                pv[2] = exp2f(sc[j][2] - MFIX);
                pv[3] = exp2f(sc[j][3] - MFIX);
                l0 += pv[0]; l1 += pv[1]; l2 += pv[2]; l3 += pv[3];
                union { bf16 h[4]; ushort4 s4; } u;
#pragma unroll
                for (int r = 0; r < 4; ++r) u.h[r] = __float2bfloat16(pv[r]);
                *(ushort4*)(&Pl[wave][st][lr][j * 16 + lk * 4]) = u.s4;
            }
            ssum += (l0 + l1) + (l2 + l3);
        };
        auto pv = [&](f32x4* o, int st) {
#pragma unroll
            for (int ks = 0; ks < 2; ++ks) {
                const bf16x8 pf = *(const bf16x8*)(&Pl[wave][st][lr][ks * 32 + lk * 8]);
                __builtin_amdgcn_s_setprio(1);
#pragma unroll
                for (int j = 0; j < 4; ++j)
                    o[j] = __builtin_amdgcn_mfma_f32_16x16x32_bf16(vf[ks][j], pf, o[j], 0, 0, 0);
                __builtin_amdgcn_s_setprio(0);
            }
        };

        smx(scB, sB, qB, kt == tB, 1);
        if (doA) smx(scA, sA, qA, kt == tA, 0);
        pv(oB, 1);
        if (doA) pv(oA, 0);

        __builtin_amdgcn_sched_barrier(0);
        __builtin_amdgcn_s_barrier();   // all reads of buf c done before next stage overwrites
    }

    const int b = bh >> 4, h = bh & 15;
    // normalized final store
    auto epiF = [&](float ssum, f32x4* o, int qX) {
        float s = ssum;
        s += __shfl_xor(s, 16);
        s += __shfl_xor(s, 32);
        const float inv = 1.0f / s;
        bf16* dst = attnb + (size_t)(b * 2048 + qX + lr) * 1024 + h * 64 + lk * 4;
#pragma unroll
        for (int j = 0; j < 4; ++j) {
            union { bf16 h4[4]; ushort4 s4; } u;
#pragma unroll
            for (int r = 0; r < 4; ++r) u.h4[r] = __float2bfloat16(o[j][r] * inv);
            *(ushort4*)(dst + j * 16) = u.s4;
        }
    };
    if (hasA) epiF(sA, oA, qA);
    if (!partB) {
        epiF(sB, oB, qB);
    } else {
        // partial store: unnormalized bf16 O + per-row s
        const int x = z1 ? (xi - 16) : xi;
        const int strip = x * 32 + bh;
        float s = sB;
        s += __shfl_xor(s, 16);
        s += __shfl_xor(s, 32);
        bf16* dstO;
        float* dstS;
        if (!z1) {  // into attnb slot
            dstO = attnb + (size_t)(b * 2048 + qB + lr) * 1024 + h * 64 + lk * 4;
            dstS = sb0 + strip * 64 + wave * 16 + lr;
        } else {    // into pbuf
            dstO = pbuf + ((size_t)strip * 64 + wave * 16 + lr) * 64 + lk * 4;
            dstS = sb1 + strip * 64 + wave * 16 + lr;
        }
#pragma unroll
        for (int j = 0; j < 4; ++j) {
            union { bf16 h4[4]; ushort4 s4; } u;
#pragma unroll
            for (int r = 0; r < 4; ++r) u.h4[r] = __float2bfloat16(oB[j][r]);
            *(ushort4*)(dstO + j * 16) = u.s4;
        }
        if (lk == 0) *dstS = s;
    }
#undef STAGE
}

// ---------------- combine the k-split partials ----------------
// grid (256): strip = x*32+bh, x in [0,8). 256 threads, 16 elems each.
__global__ void combine_kernel(const bf16* __restrict__ pbuf,
                               const float* __restrict__ sb0, const float* __restrict__ sb1,
                               bf16* __restrict__ attnb)
{
    const int strip = blockIdx.x;
    const int x = strip >> 5, bh = strip & 31;
    const int tB = 31 - x;
    const int b = bh >> 4, h = bh & 15;
    const int t = threadIdx.x;
    const int row = t >> 2;               // 0..63
    const int dseg = (t & 3) * 16;
    const int qq = tB * 64 + row;
    const float s = sb0[strip * 64 + row] + sb1[strip * 64 + row];
    const float inv = 1.0f / s;
    bf16* dst = attnb + (size_t)(b * 2048 + qq) * 1024 + h * 64 + dseg;
    const bf16* p1 = pbuf + ((size_t)strip * 64 + row) * 64 + dseg;
    u16x8 a0 = *(const u16x8*)(dst);
    u16x8 a1 = *(const u16x8*)(dst + 8);
    u16x8 c0 = *(const u16x8*)(p1);
    u16x8 c1 = *(const u16x8*)(p1 + 8);
    union { bf16 h8[8]; u16x8 v; } o0, o1;
#pragma unroll
    for (int i = 0; i < 8; ++i) {
        o0.h8[i] = __float2bfloat16((b2f(a0[i]) + b2f(c0[i])) * inv);
        o1.h8[i] = __float2bfloat16((b2f(a1[i]) + b2f(c1[i])) * inv);
    }
    *(u16x8*)(dst)     = o0.v;
    *(u16x8*)(dst + 8) = o1.v;
}

// ---------------- launch ----------------
extern "C" void kernel_launch(void* const* d_in, const int* in_sizes, int n_in,
                              void* d_out, int out_size, void* d_ws, size_t ws_size,
                              hipStream_t stream)
{
    const float* x   = (const float*)d_in[0];
    const float* wq  = (const float*)d_in[1];
    const float* wk  = (const float*)d_in[2];
    const float* wv  = (const float*)d_in[3];
    const float* wo  = (const float*)d_in[4];
    const int*   pos = (const int*)d_in[5];
    const void* theta = d_in[6];

    char* ws = (char*)d_ws;
    bf16* xb    = (bf16*)(ws + OFF_XB);
    bf16* attnb = (bf16*)(ws + OFF_XB);    // reuse: xb consumed before attn writes
    bf16* wqkvb = (bf16*)(ws + OFF_WQKVB);
    bf16* pbuf  = (bf16*)(ws + OFF_PBUF);  // aliases wqkvb (free during attn)
    float* sb0  = (float*)(ws + OFF_SB0);
    float* sb1  = (float*)(ws + OFF_SB1);
    bf16* wob   = (bf16*)(ws + OFF_WOB);
    bf16* qb    = (bf16*)(ws + OFF_QB);
    bf16* kb    = (bf16*)(ws + OFF_KB);
    bf16* vtb   = (bf16*)(ws + OFF_VTB);
    float* cst  = (float*)(ws + OFF_CS);
    float* snt  = (float*)(ws + OFF_SN);

    prep_kernel<<<dim3(4096, 6), 256, 0, stream>>>(x, wq, wk, wv, wo, xb, wqkvb, wob,
                                                   pos, theta, cst, snt);
    gemm_bt<0, 128><<<dim3(32, 24), 256, 0, stream>>>(xb, wqkvb, 1024, 3072, nullptr,
                                                      qb, kb, vtb, cst, snt);
    attn_kernel<<<dim3(24, 32), 256, 0, stream>>>(qb, kb, vtb, attnb, pbuf, sb0, sb1);
    combine_kernel<<<256, 256, 0, stream>>>(pbuf, sb0, sb1, attnb);
    gemm_bt<1, 64><<<dim3(64, 8), 256, 0, stream>>>(attnb, wob, 1024, 1024, (float*)d_out,
                                                    nullptr, nullptr, nullptr, nullptr, nullptr);
}

// Round 14
// 141.845 us; speedup vs baseline: 1.1322x; 1.1322x over previous
//
#include <hip/hip_runtime.h>
#include <hip/hip_bf16.h>
#include <stdint.h>

typedef __attribute__((ext_vector_type(8))) __bf16 bf16x8;
typedef __attribute__((ext_vector_type(4))) float f32x4;
typedef __hip_bfloat16 bf16;

#define GLDS(g, l) __builtin_amdgcn_global_load_lds( \
    (const __attribute__((address_space(1))) void*)(g), \
    (__attribute__((address_space(3))) void*)(l), 16, 0, 0)

#define SCALE_Q 0.18033688f   // 0.125 * log2(e): softmax runs in exp2 domain
#define MFIX 12.0f            // fixed softmax max (log2 domain)

// ---------------- workspace layout (bytes) ----------------
#define OFF_XB     ((size_t)0)          // 4096*1024 bf16 = 8388608  (reused as attnb)
#define OFF_WQKVB  ((size_t)8388608)    // 3072*1024 bf16 = 6291456
#define OFF_WOB    ((size_t)14680064)   // 1024*1024 bf16 = 2097152
#define OFF_QB     ((size_t)16777216)   // 32*2048*64 bf16 = 8388608
#define OFF_KB     ((size_t)25165824)
#define OFF_VTB    ((size_t)33554432)
#define OFF_CS     ((size_t)41943040)   // 2048*32 f32 = 262144
#define OFF_SN     ((size_t)42205184)

// ---------------- fp32 -> bf16 conversion + RoPE table (region 5) ----------------
__global__ void prep_kernel(const float* __restrict__ x, const float* __restrict__ wq,
                            const float* __restrict__ wk, const float* __restrict__ wv,
                            const float* __restrict__ wo,
                            bf16* __restrict__ xb, bf16* __restrict__ wqkvb,
                            bf16* __restrict__ wob,
                            const int* __restrict__ pos, const void* __restrict__ theta_p,
                            float* __restrict__ cst, float* __restrict__ snt)
{
    const int region = blockIdx.y;
    if (region == 5) {                      // RoPE cos/sin table: [s][i], i = d/2
        if (blockIdx.x >= 256) return;
        const int t = blockIdx.x * 256 + threadIdx.x;   // 2048*32 = 65536
        const int s = t >> 5, i = t & 31;
        const int ti = ((const int*)theta_p)[0];
        const float theta = (ti > 0 && ti < 100000000) ? (float)ti : ((const float*)theta_p)[0];
        const float fr = expf(-(float)i * (1.0f / 32.0f) * logf(theta));
        const float ang = (float)pos[s] * fr;
        cst[t] = cosf(ang);
        snt[t] = sinf(ang);
        return;
    }
    const float* src;
    bf16* dst;
    int count;
    switch (region) {
        case 0:  src = x;  dst = xb;              count = 4096 * 1024; break;
        case 1:  src = wq; dst = wqkvb;           count = 1024 * 1024; break;
        case 2:  src = wk; dst = wqkvb + 1048576; count = 1024 * 1024; break;
        case 3:  src = wv; dst = wqkvb + 2097152; count = 1024 * 1024; break;
        default: src = wo; dst = wob;             count = 1024 * 1024; break;
    }
    const int i = (blockIdx.x * 256 + threadIdx.x) * 4;
    if (i >= count) return;
    const float4 v = *(const float4*)(src + i);
    union { bf16 h[4]; short4 s4; } u;
    u.h[0] = __float2bfloat16(v.x);
    u.h[1] = __float2bfloat16(v.y);
    u.h[2] = __float2bfloat16(v.z);
    u.h[3] = __float2bfloat16(v.w);
    *(short4*)(dst + i) = u.s4;
}

// ---------------- GEMM: C[M,N] = A[M,K] * B[N,K]^T, bf16 in, fp32 acc ----------------
// BM x 128 tile, BK=64, 4 waves (2x2). Asl/Bsl in a shared pool with
// seg^(row&7) XOR swizzle. MODE 0: QKV epilogue; V tiles are transposed
// through LDS (Tl aliases the pool, stride 130) and stored as coalesced
// 256B rows of vtb (4 rows x 16 lanes x 16B per instr). Q/K direct.
// MODE 1: fp32 row-major store. XCD-swizzled block remap (nwg % 8 == 0).
template<int MODE, int BM>
__global__ __launch_bounds__(256) void gemm_bt(
    const bf16* __restrict__ A, const bf16* __restrict__ B,
    const int K, const int N,
    float* __restrict__ outf,
    bf16* __restrict__ qb, bf16* __restrict__ kb, bf16* __restrict__ vtb,
    const float* __restrict__ cst, const float* __restrict__ snt)
{
    constexpr int NF = BM / 32;
    constexpr int ABSZ = (BM * 64 + 128 * 64) * 2;
    constexpr int TLSZ = (MODE == 0) ? 128 * 130 * 2 : 0;
    constexpr int POOL = ABSZ > TLSZ ? ABSZ : TLSZ;
    __shared__ __align__(16) char smem[POOL];
    bf16* Asl = (bf16*)smem;
    bf16* Bsl = (bf16*)(smem + (size_t)BM * 64 * 2);
    const int tid = threadIdx.x;
    const int wave = tid >> 6, lane = tid & 63;
    const int lr = lane & 15, lk = lane >> 4;

    // bijective XCD swizzle
    const int nwg = gridDim.x * gridDim.y;
    const int flat = blockIdx.y * gridDim.x + blockIdx.x;
    const int wg = (flat & 7) * (nwg >> 3) + (flat >> 3);
    const int m0 = (wg % gridDim.x) * BM;
    const int n0 = (wg / gridDim.x) * 128;

    const int wm = (wave >> 1) * (BM / 2);
    const int wn = (wave & 1) * 64;
    const int srow = tid >> 3, sseg = tid & 7;
    const int swel = (sseg ^ (srow & 7)) * 8;    // pre-swizzled element offset in row

    f32x4 acc[NF][4] = {};

    const bf16* aRow = A + (size_t)(m0 + srow) * K + swel;
    const bf16* bRow = B + (size_t)(n0 + srow) * K + swel;
    char* lA = (char*)Asl + tid * 16;
    char* lB = (char*)Bsl + tid * 16;
    const size_t rowK32 = (size_t)32 * K;

    for (int k0 = 0; k0 < K; k0 += 64) {
#pragma unroll
        for (int g = 0; g < NF; ++g)
            GLDS(aRow + k0 + g * rowK32, lA + g * 4096);
#pragma unroll
        for (int g = 0; g < 4; ++g)
            GLDS(bRow + k0 + g * rowK32, lB + g * 4096);
        __syncthreads();
#pragma unroll
        for (int kk = 0; kk < 2; ++kk) {
            const int s = kk * 4 + lk;           // 16B segment for this fragment
            bf16x8 af[NF], bfr[4];
#pragma unroll
            for (int i = 0; i < NF; ++i) {
                const int R = wm + i * 16 + lr;
                af[i] = *(const bf16x8*)((const char*)Asl + R * 128 + (((s) ^ (R & 7)) << 4));
            }
#pragma unroll
            for (int j = 0; j < 4; ++j) {
                const int R = wn + j * 16 + lr;
                bfr[j] = *(const bf16x8*)((const char*)Bsl + R * 128 + (((s) ^ (R & 7)) << 4));
            }
#pragma unroll
            for (int i = 0; i < NF; ++i)
#pragma unroll
                for (int j = 0; j < 4; ++j)
                    acc[i][j] = __builtin_amdgcn_mfma_f32_16x16x32_bf16(af[i], bfr[j], acc[i][j], 0, 0, 0);
        }
        __syncthreads();
    }

    if constexpr (MODE == 1) {
#pragma unroll
        for (int i = 0; i < NF; ++i)
#pragma unroll
            for (int j = 0; j < 4; ++j)
#pragma unroll
                for (int r = 0; r < 4; ++r) {
                    const int row = m0 + wm + i * 16 + lk * 4 + r;
                    const int col = n0 + wn + j * 16 + lr;
                    outf[(size_t)row * N + col] = acc[i][j][r];
                }
    } else {
        const int matn = n0 >> 10;   // 0=Q 1=K 2=V, uniform per block
        if (matn == 2) {
            // V: transpose 128x128 tile via LDS, then coalesced 256B-row stores.
            bf16* Tl = (bf16*)smem;          // aliases Asl/Bsl; safe after last barrier
#pragma unroll
            for (int i = 0; i < NF; ++i)
#pragma unroll
                for (int j = 0; j < 4; ++j)
#pragma unroll
                    for (int r = 0; r < 4; ++r) {
                        const int trow = wm + i * 16 + lk * 4 + r;   // s-local
                        const int tcol = wn + j * 16 + lr;           // col-local
                        Tl[tcol * 130 + trow] = __float2bfloat16(acc[i][j][r]);
                    }
            __syncthreads();
            const int b = m0 >> 11;
            const int s0 = m0 & 2047;
#pragma unroll
            for (int k = 0; k < 8; ++k) {
                const int c = wave * 32 + k * 4 + (lane >> 4);       // tile col
                const int e = (n0 + c) & 1023;
                const size_t bhi = (size_t)(b * 16 + (e >> 6));
                bf16* dst = vtb + (bhi * 64 + (e & 63)) * 2048 + s0 + lr * 8;
                *(uint4*)dst = *(const uint4*)&Tl[c * 130 + lr * 8];
            }
        } else {
#pragma unroll
            for (int i = 0; i < NF; ++i)
#pragma unroll
                for (int j = 0; j < 4; ++j)
#pragma unroll
                    for (int r = 0; r < 4; ++r) {
                        const int row = m0 + wm + i * 16 + lk * 4 + r;
                        const int col = n0 + wn + j * 16 + lr;
                        float v = acc[i][j][r];
                        float p = __shfl_xor(v, 1);        // RoPE pair partner
                        const int e = col & 1023;
                        const int h = e >> 6;
                        const int dd = e & 63;
                        const int b = row >> 11;
                        const int s = row & 2047;
                        const size_t bhi = (size_t)(b * 16 + h);
                        const float cs = cst[s * 32 + (dd >> 1)];
                        const float sn = snt[s * 32 + (dd >> 1)];
                        const float rv = (dd & 1) ? (p * sn + v * cs) : (v * cs - p * sn);
                        if (matn == 0)
                            qb[(bhi * 2048 + s) * 64 + dd] = __float2bfloat16(rv * SCALE_Q);
                        else
                            kb[(bhi * 2048 + s) * 64 + dd] = __float2bfloat16(rv);
                    }
        }
    }
}

// ---------------- causal flash attention (R12 structure) ----------------
// Balanced pairing: block x processes q-strips (x, 31-x), 33 tile-visits,
// shared K/V stream, kf shared, vf hoisted to regs. Swapped QK^T: lane owns
// one q-row. FIXED-MAX softmax: P = exp2(sc - MFIX). Dual Pl strips.
__global__ __launch_bounds__(256) void attn_kernel(
    const bf16* __restrict__ qb, const bf16* __restrict__ kb,
    const bf16* __restrict__ vtb, bf16* __restrict__ attnb)
{
    __shared__ __align__(16) bf16 Kl[2][64 * 64];
    __shared__ __align__(16) bf16 Vl[2][64 * 64];
    __shared__ __align__(16) bf16 Pl[4][2][16][72];   // [wave][strip][q][k], 144B rows
    const int tid = threadIdx.x;
    const int wave = tid >> 6, lane = tid & 63;
    const int lr = lane & 15, lk = lane >> 4;
    const int tA = blockIdx.x;            // 0..15  (short strip)
    const int tB = 31 - tA;               // 16..31 (long strip)
    const int bh = blockIdx.y;
    const int qA = tA * 64 + wave * 16;
    const int qB = tB * 64 + wave * 16;

    const bf16* Qp = qb + (size_t)bh * 2048 * 64;
    const bf16* Kp = kb + (size_t)bh * 2048 * 64;
    const bf16* Vp = vtb + (size_t)bh * 64 * 2048;

    const int srow = tid >> 3;
    const int sseg = tid & 7;
    const int sw16 = (sseg ^ (srow & 7)) * 16;
    const char* kg = (const char*)Kp + (size_t)srow * 128 + sw16;
    const char* vg = (const char*)Vp + (size_t)srow * 4096 + sw16;

#define STAGE(kt_, c_) do {                                              \
        const char* kgt = kg + (size_t)(kt_) * 8192;                     \
        GLDS(kgt,              &Kl[c_][0] + tid * 8);                    \
        GLDS(kgt + 32 * 128,   &Kl[c_][0] + 2048 + tid * 8);             \
        const char* vgt = vg + (size_t)(kt_) * 128;                      \
        GLDS(vgt,              &Vl[c_][0] + tid * 8);                    \
        GLDS(vgt + 32 * 4096,  &Vl[c_][0] + 2048 + tid * 8);             \
    } while (0)

    bf16x8 qfA[2], qfB[2];
#pragma unroll
    for (int ks = 0; ks < 2; ++ks) {
        qfA[ks] = *(const bf16x8*)(Qp + (qA + lr) * 64 + ks * 32 + lk * 8);
        qfB[ks] = *(const bf16x8*)(Qp + (qB + lr) * 64 + ks * 32 + lk * 8);
    }

    float sA = 0.f, sB = 0.f;
    f32x4 oA[4] = {}, oB[4] = {};

    STAGE(0, 0);

    const int xoff = (lr & 7) * 8;   // K/V swizzle: row&7 == lr&7 for rows j*16+lr

    for (int kt = 0; kt <= tB; ++kt) {
        const int c = kt & 1;
        const int kv0 = kt * 64;
        const bool doA = (kt <= tA);
        if (kt < tB) {
            STAGE(kt + 1, c ^ 1);
            asm volatile("s_waitcnt vmcnt(4)" ::: "memory");  // kt landed; kt+1 in flight
        } else {
            asm volatile("s_waitcnt vmcnt(0)" ::: "memory");
        }
        __builtin_amdgcn_s_barrier();
        __builtin_amdgcn_sched_barrier(0);
        const bf16* Kc = &Kl[c][0];
        const bf16* Vc = &Vl[c][0];

        // ---- QK^T (swapped): scX[j][r] = P^T[k = j*16+lk*4+r][q = lr] ----
        f32x4 scB[4] = {}, scA[4] = {};
#pragma unroll
        for (int ks = 0; ks < 2; ++ks) {
            bf16x8 kf[4];
#pragma unroll
            for (int j = 0; j < 4; ++j)
                kf[j] = *(const bf16x8*)(Kc + (j * 16 + lr) * 64 + ((ks * 32 + lk * 8) ^ xoff));
            __builtin_amdgcn_s_setprio(1);
#pragma unroll
            for (int j = 0; j < 4; ++j)
                scB[j] = __builtin_amdgcn_mfma_f32_16x16x32_bf16(kf[j], qfB[ks], scB[j], 0, 0, 0);
            if (doA) {
#pragma unroll
                for (int j = 0; j < 4; ++j)
                    scA[j] = __builtin_amdgcn_mfma_f32_16x16x32_bf16(kf[j], qfA[ks], scA[j], 0, 0, 0);
            }
            __builtin_amdgcn_s_setprio(0);
        }

        // vf hoisted once per visit; loads overlap the softmax below
        bf16x8 vf[2][4];
#pragma unroll
        for (int ks = 0; ks < 2; ++ks)
#pragma unroll
            for (int j = 0; j < 4; ++j)
                vf[ks][j] = *(const bf16x8*)(Vc + (j * 16 + lr) * 64 + ((ks * 32 + lk * 8) ^ xoff));

        // ---- fixed-max softmax: P = exp2(sc - MFIX); branchless, lane-local ----
        auto smx = [&](f32x4* sc, float& ssum, int qX, bool diag, int st) {
            if (diag) {
#pragma unroll
                for (int j = 0; j < 4; ++j)
#pragma unroll
                    for (int r = 0; r < 4; ++r)
                        if (kv0 + j * 16 + lk * 4 + r > qX + lr) sc[j][r] = -1e30f;
            }
            float l0 = 0.f, l1 = 0.f, l2 = 0.f, l3 = 0.f;
#pragma unroll
            for (int j = 0; j < 4; ++j) {
                float pv[4];
                pv[0] = exp2f(sc[j][0] - MFIX);
                pv[1] = exp2f(sc[j][1] - MFIX);
                pv[2] = exp2f(sc[j][2] - MFIX);
                pv[3] = exp2f(sc[j][3] - MFIX);
                l0 += pv[0]; l1 += pv[1]; l2 += pv[2]; l3 += pv[3];
                union { bf16 h[4]; ushort4 s4; } u;
#pragma unroll
                for (int r = 0; r < 4; ++r) u.h[r] = __float2bfloat16(pv[r]);
                *(ushort4*)(&Pl[wave][st][lr][j * 16 + lk * 4]) = u.s4;
            }
            ssum += (l0 + l1) + (l2 + l3);
        };
        // ---- PV for strip st: o[j] (= O^T[d][q]) += mfma(vf, pf) ----
        auto pv = [&](f32x4* o, int st) {
#pragma unroll
            for (int ks = 0; ks < 2; ++ks) {
                const bf16x8 pf = *(const bf16x8*)(&Pl[wave][st][lr][ks * 32 + lk * 8]);
                __builtin_amdgcn_s_setprio(1);
#pragma unroll
                for (int j = 0; j < 4; ++j)
                    o[j] = __builtin_amdgcn_mfma_f32_16x16x32_bf16(vf[ks][j], pf, o[j], 0, 0, 0);
                __builtin_amdgcn_s_setprio(0);
            }
        };

        smx(scB, sB, qB, kt == tB, 1);
        if (doA) smx(scA, sA, qA, kt == tA, 0);
        pv(oB, 1);
        if (doA) pv(oA, 0);

        __builtin_amdgcn_sched_barrier(0);
        __builtin_amdgcn_s_barrier();   // all reads of buf c done before next stage overwrites
    }

    const int b = bh >> 4, h = bh & 15;
    auto epi = [&](float ssum, f32x4* o, int qX) {
        float s = ssum;
        s += __shfl_xor(s, 16);
        s += __shfl_xor(s, 32);
        const float inv = 1.0f / s;
        const int qq = qX + lr;
        bf16* dst = attnb + (size_t)(b * 2048 + qq) * 1024 + h * 64 + lk * 4;
#pragma unroll
        for (int j = 0; j < 4; ++j) {
            union { bf16 h4[4]; ushort4 s4; } u;
#pragma unroll
            for (int r = 0; r < 4; ++r) u.h4[r] = __float2bfloat16(o[j][r] * inv);
            *(ushort4*)(dst + j * 16) = u.s4;
        }
    };
    epi(sA, oA, qA);
    epi(sB, oB, qB);
#undef STAGE
}

// ---------------- launch ----------------
extern "C" void kernel_launch(void* const* d_in, const int* in_sizes, int n_in,
                              void* d_out, int out_size, void* d_ws, size_t ws_size,
                              hipStream_t stream)
{
    const float* x   = (const float*)d_in[0];
    const float* wq  = (const float*)d_in[1];
    const float* wk  = (const float*)d_in[2];
    const float* wv  = (const float*)d_in[3];
    const float* wo  = (const float*)d_in[4];
    const int*   pos = (const int*)d_in[5];
    const void* theta = d_in[6];

    char* ws = (char*)d_ws;
    bf16* xb    = (bf16*)(ws + OFF_XB);
    bf16* attnb = (bf16*)(ws + OFF_XB);    // reuse: xb consumed before attn writes
    bf16* wqkvb = (bf16*)(ws + OFF_WQKVB);
    bf16* wob   = (bf16*)(ws + OFF_WOB);
    bf16* qb    = (bf16*)(ws + OFF_QB);
    bf16* kb    = (bf16*)(ws + OFF_KB);
    bf16* vtb   = (bf16*)(ws + OFF_VTB);
    float* cst  = (float*)(ws + OFF_CS);
    float* snt  = (float*)(ws + OFF_SN);

    prep_kernel<<<dim3(4096, 6), 256, 0, stream>>>(x, wq, wk, wv, wo, xb, wqkvb, wob,
                                                   pos, theta, cst, snt);
    gemm_bt<0, 128><<<dim3(32, 24), 256, 0, stream>>>(xb, wqkvb, 1024, 3072, nullptr,
                                                      qb, kb, vtb, cst, snt);
    attn_kernel<<<dim3(16, 32), 256, 0, stream>>>(qb, kb, vtb, attnb);
    gemm_bt<1, 64><<<dim3(64, 8), 256, 0, stream>>>(attnb, wob, 1024, 1024, (float*)d_out,
                                                    nullptr, nullptr, nullptr, nullptr, nullptr);
}

// Round 15
// 131.575 us; speedup vs baseline: 1.2206x; 1.0781x over previous
//
#include <hip/hip_runtime.h>
#include <hip/hip_bf16.h>
#include <stdint.h>

typedef __attribute__((ext_vector_type(8))) __bf16 bf16x8;
typedef __attribute__((ext_vector_type(4))) float f32x4;
typedef __hip_bfloat16 bf16;

#define GLDS(g, l) __builtin_amdgcn_global_load_lds( \
    (const __attribute__((address_space(1))) void*)(g), \
    (__attribute__((address_space(3))) void*)(l), 16, 0, 0)

#define SCALE_Q 0.18033688f   // 0.125 * log2(e): softmax runs in exp2 domain
#define MFIX 12.0f            // fixed softmax max (log2 domain)

// ---------------- workspace layout (bytes) ----------------
#define OFF_XB     ((size_t)0)          // 4096*1024 bf16 = 8388608  (reused as attnb)
#define OFF_WQKVB  ((size_t)8388608)    // 3072*1024 bf16 = 6291456
#define OFF_WOB    ((size_t)14680064)   // 1024*1024 bf16 = 2097152
#define OFF_QB     ((size_t)16777216)   // 32*2048*64 bf16 = 8388608
#define OFF_KB     ((size_t)25165824)
#define OFF_VTB    ((size_t)33554432)
#define OFF_CS     ((size_t)41943040)   // 2048*32 f32 = 262144
#define OFF_SN     ((size_t)42205184)

// ---------------- fp32 -> bf16 conversion + RoPE table (region 5) ----------------
__global__ void prep_kernel(const float* __restrict__ x, const float* __restrict__ wq,
                            const float* __restrict__ wk, const float* __restrict__ wv,
                            const float* __restrict__ wo,
                            bf16* __restrict__ xb, bf16* __restrict__ wqkvb,
                            bf16* __restrict__ wob,
                            const int* __restrict__ pos, const void* __restrict__ theta_p,
                            float* __restrict__ cst, float* __restrict__ snt)
{
    const int region = blockIdx.y;
    if (region == 5) {                      // RoPE cos/sin table: [s][i], i = d/2
        if (blockIdx.x >= 256) return;
        const int t = blockIdx.x * 256 + threadIdx.x;   // 2048*32 = 65536
        const int s = t >> 5, i = t & 31;
        const int ti = ((const int*)theta_p)[0];
        const float theta = (ti > 0 && ti < 100000000) ? (float)ti : ((const float*)theta_p)[0];
        const float fr = expf(-(float)i * (1.0f / 32.0f) * logf(theta));
        const float ang = (float)pos[s] * fr;
        cst[t] = cosf(ang);
        snt[t] = sinf(ang);
        return;
    }
    const float* src;
    bf16* dst;
    int count;
    switch (region) {
        case 0:  src = x;  dst = xb;              count = 4096 * 1024; break;
        case 1:  src = wq; dst = wqkvb;           count = 1024 * 1024; break;
        case 2:  src = wk; dst = wqkvb + 1048576; count = 1024 * 1024; break;
        case 3:  src = wv; dst = wqkvb + 2097152; count = 1024 * 1024; break;
        default: src = wo; dst = wob;             count = 1024 * 1024; break;
    }
    const int i = (blockIdx.x * 256 + threadIdx.x) * 4;
    if (i >= count) return;
    const float4 v = *(const float4*)(src + i);
    union { bf16 h[4]; short4 s4; } u;
    u.h[0] = __float2bfloat16(v.x);
    u.h[1] = __float2bfloat16(v.y);
    u.h[2] = __float2bfloat16(v.z);
    u.h[3] = __float2bfloat16(v.w);
    *(short4*)(dst + i) = u.s4;
}

// ---------------- GEMM: C[M,N] = A[M,K] * B[N,K]^T, bf16 in, fp32 acc ----------------
// BM x 128 tile, BK=32, 4 waves (2x2), DOUBLE-BUFFERED LDS with counted-vmcnt
// prefetch (attn-proven loop: STAGE(k+1); vmcnt(n); barrier; compute; barrier).
// Rows are 64B; swizzle index t(row) = (row + (row>>2)) & 3 applied to the
// pre-swizzled global source and the ds_read (worst 2-way banks = free).
// MODE 0: QKV epilogue (RoPE scatter; V transposed via LDS, coalesced stores).
// MODE 1: fp32 row-major store. XCD-swizzled block remap (nwg % 8 == 0).
template<int MODE, int BM>
__global__ __launch_bounds__(256) void gemm_bt(
    const bf16* __restrict__ A, const bf16* __restrict__ B,
    const int K, const int N,
    float* __restrict__ outf,
    bf16* __restrict__ qb, bf16* __restrict__ kb, bf16* __restrict__ vtb,
    const float* __restrict__ cst, const float* __restrict__ snt)
{
    constexpr int NF = BM / 32;              // per-wave A fragments
    constexpr int AG = BM / 64;              // A staging GLDS per step (64 rows each)
    constexpr int ABYTES = BM * 64;          // one A buffer (BM rows x 64B)
    constexpr int BBYTES = 128 * 64;         // one B buffer
    constexpr int DBSZ = 2 * (ABYTES + BBYTES);
    constexpr int TLSZ = (MODE == 0) ? 128 * 130 * 2 : 0;
    constexpr int POOL = DBSZ > TLSZ ? DBSZ : TLSZ;
    __shared__ __align__(16) char smem[POOL];
    const int tid = threadIdx.x;
    const int wave = tid >> 6, lane = tid & 63;
    const int lr = lane & 15, lk = lane >> 4;

    // bijective XCD swizzle
    const int nwg = gridDim.x * gridDim.y;
    const int flat = blockIdx.y * gridDim.x + blockIdx.x;
    const int wg = (flat & 7) * (nwg >> 3) + (flat >> 3);
    const int m0 = (wg % gridDim.x) * BM;
    const int n0 = (wg / gridDim.x) * 128;

    const int wm = (wave >> 1) * (BM / 2);
    const int wn = (wave & 1) * 64;
    const int srow = tid >> 2, sseg = tid & 3;                     // 64 rows x 4 segs
    const int swel = (sseg ^ ((srow + (srow >> 2)) & 3)) * 8;      // pre-swizzled elems

    f32x4 acc[NF][4] = {};

    const bf16* aRow = A + (size_t)(m0 + srow) * K + swel;
    const bf16* bRow = B + (size_t)(n0 + srow) * K + swel;
    const size_t rowK64 = (size_t)64 * K;

    auto STAGE = [&](int step, int c) {
        char* lA = smem + c * ABYTES + tid * 16;
        char* lB = smem + 2 * ABYTES + c * BBYTES + tid * 16;
        const int off = step * 32;
#pragma unroll
        for (int g = 0; g < AG; ++g)
            GLDS(aRow + off + (size_t)g * rowK64, lA + g * 4096);
#pragma unroll
        for (int g = 0; g < 2; ++g)
            GLDS(bRow + off + (size_t)g * rowK64, lB + g * 4096);
    };

    const int xoff = (lk ^ ((lr + (lr >> 2)) & 3)) << 4;   // read-side swizzle (lane const)
    const int NSTEP = K >> 5;

    STAGE(0, 0);

    for (int ks = 0; ks < NSTEP; ++ks) {
        const int c = ks & 1;
        if (ks < NSTEP - 1) {
            STAGE(ks + 1, c ^ 1);
            if constexpr (AG == 2) asm volatile("s_waitcnt vmcnt(4)" ::: "memory");
            else                   asm volatile("s_waitcnt vmcnt(3)" ::: "memory");
        } else {
            asm volatile("s_waitcnt vmcnt(0)" ::: "memory");
        }
        __builtin_amdgcn_s_barrier();
        __builtin_amdgcn_sched_barrier(0);
        const char* aBase = smem + c * ABYTES;
        const char* bBase = smem + 2 * ABYTES + c * BBYTES;

        bf16x8 af[NF], bfr[4];
#pragma unroll
        for (int i = 0; i < NF; ++i)
            af[i] = *(const bf16x8*)(aBase + (wm + i * 16 + lr) * 64 + xoff);
#pragma unroll
        for (int j = 0; j < 4; ++j)
            bfr[j] = *(const bf16x8*)(bBase + (wn + j * 16 + lr) * 64 + xoff);
#pragma unroll
        for (int i = 0; i < NF; ++i)
#pragma unroll
            for (int j = 0; j < 4; ++j)
                acc[i][j] = __builtin_amdgcn_mfma_f32_16x16x32_bf16(af[i], bfr[j], acc[i][j], 0, 0, 0);
        __builtin_amdgcn_sched_barrier(0);
        __builtin_amdgcn_s_barrier();
    }

    if constexpr (MODE == 1) {
#pragma unroll
        for (int i = 0; i < NF; ++i)
#pragma unroll
            for (int j = 0; j < 4; ++j)
#pragma unroll
                for (int r = 0; r < 4; ++r) {
                    const int row = m0 + wm + i * 16 + lk * 4 + r;
                    const int col = n0 + wn + j * 16 + lr;
                    outf[(size_t)row * N + col] = acc[i][j][r];
                }
    } else {
        const int matn = n0 >> 10;   // 0=Q 1=K 2=V, uniform per block
        if (matn == 2) {
            // V: transpose 128x128 tile via LDS, then coalesced 256B-row stores.
            bf16* Tl = (bf16*)smem;          // aliases buffers; safe after last barrier
#pragma unroll
            for (int i = 0; i < NF; ++i)
#pragma unroll
                for (int j = 0; j < 4; ++j)
#pragma unroll
                    for (int r = 0; r < 4; ++r) {
                        const int trow = wm + i * 16 + lk * 4 + r;   // s-local
                        const int tcol = wn + j * 16 + lr;           // col-local
                        Tl[tcol * 130 + trow] = __float2bfloat16(acc[i][j][r]);
                    }
            __syncthreads();
            const int b = m0 >> 11;
            const int s0 = m0 & 2047;
#pragma unroll
            for (int k = 0; k < 8; ++k) {
                const int c = wave * 32 + k * 4 + (lane >> 4);       // tile col
                const int e = (n0 + c) & 1023;
                const size_t bhi = (size_t)(b * 16 + (e >> 6));
                bf16* dst = vtb + (bhi * 64 + (e & 63)) * 2048 + s0 + lr * 8;
                *(uint4*)dst = *(const uint4*)&Tl[c * 130 + lr * 8];
            }
        } else {
#pragma unroll
            for (int i = 0; i < NF; ++i)
#pragma unroll
                for (int j = 0; j < 4; ++j)
#pragma unroll
                    for (int r = 0; r < 4; ++r) {
                        const int row = m0 + wm + i * 16 + lk * 4 + r;
                        const int col = n0 + wn + j * 16 + lr;
                        float v = acc[i][j][r];
                        float p = __shfl_xor(v, 1);        // RoPE pair partner
                        const int e = col & 1023;
                        const int h = e >> 6;
                        const int dd = e & 63;
                        const int b = row >> 11;
                        const int s = row & 2047;
                        const size_t bhi = (size_t)(b * 16 + h);
                        const float cs = cst[s * 32 + (dd >> 1)];
                        const float sn = snt[s * 32 + (dd >> 1)];
                        const float rv = (dd & 1) ? (p * sn + v * cs) : (v * cs - p * sn);
                        if (matn == 0)
                            qb[(bhi * 2048 + s) * 64 + dd] = __float2bfloat16(rv * SCALE_Q);
                        else
                            kb[(bhi * 2048 + s) * 64 + dd] = __float2bfloat16(rv);
                    }
        }
    }
}

// ---------------- causal flash attention (R12/R14 structure, unchanged) ----------------
__global__ __launch_bounds__(256) void attn_kernel(
    const bf16* __restrict__ qb, const bf16* __restrict__ kb,
    const bf16* __restrict__ vtb, bf16* __restrict__ attnb)
{
    __shared__ __align__(16) bf16 Kl[2][64 * 64];
    __shared__ __align__(16) bf16 Vl[2][64 * 64];
    __shared__ __align__(16) bf16 Pl[4][2][16][72];   // [wave][strip][q][k], 144B rows
    const int tid = threadIdx.x;
    const int wave = tid >> 6, lane = tid & 63;
    const int lr = lane & 15, lk = lane >> 4;
    const int tA = blockIdx.x;            // 0..15  (short strip)
    const int tB = 31 - tA;               // 16..31 (long strip)
    const int bh = blockIdx.y;
    const int qA = tA * 64 + wave * 16;
    const int qB = tB * 64 + wave * 16;

    const bf16* Qp = qb + (size_t)bh * 2048 * 64;
    const bf16* Kp = kb + (size_t)bh * 2048 * 64;
    const bf16* Vp = vtb + (size_t)bh * 64 * 2048;

    const int srow = tid >> 3;
    const int sseg = tid & 7;
    const int sw16 = (sseg ^ (srow & 7)) * 16;
    const char* kg = (const char*)Kp + (size_t)srow * 128 + sw16;
    const char* vg = (const char*)Vp + (size_t)srow * 4096 + sw16;

#define STAGE(kt_, c_) do {                                              \
        const char* kgt = kg + (size_t)(kt_) * 8192;                     \
        GLDS(kgt,              &Kl[c_][0] + tid * 8);                    \
        GLDS(kgt + 32 * 128,   &Kl[c_][0] + 2048 + tid * 8);             \
        const char* vgt = vg + (size_t)(kt_) * 128;                      \
        GLDS(vgt,              &Vl[c_][0] + tid * 8);                    \
        GLDS(vgt + 32 * 4096,  &Vl[c_][0] + 2048 + tid * 8);             \
    } while (0)

    bf16x8 qfA[2], qfB[2];
#pragma unroll
    for (int ks = 0; ks < 2; ++ks) {
        qfA[ks] = *(const bf16x8*)(Qp + (qA + lr) * 64 + ks * 32 + lk * 8);
        qfB[ks] = *(const bf16x8*)(Qp + (qB + lr) * 64 + ks * 32 + lk * 8);
    }

    float sA = 0.f, sB = 0.f;
    f32x4 oA[4] = {}, oB[4] = {};

    STAGE(0, 0);

    const int xoff = (lr & 7) * 8;   // K/V swizzle: row&7 == lr&7 for rows j*16+lr

    for (int kt = 0; kt <= tB; ++kt) {
        const int c = kt & 1;
        const int kv0 = kt * 64;
        const bool doA = (kt <= tA);
        if (kt < tB) {
            STAGE(kt + 1, c ^ 1);
            asm volatile("s_waitcnt vmcnt(4)" ::: "memory");  // kt landed; kt+1 in flight
        } else {
            asm volatile("s_waitcnt vmcnt(0)" ::: "memory");
        }
        __builtin_amdgcn_s_barrier();
        __builtin_amdgcn_sched_barrier(0);
        const bf16* Kc = &Kl[c][0];
        const bf16* Vc = &Vl[c][0];

        // ---- QK^T (swapped): scX[j][r] = P^T[k = j*16+lk*4+r][q = lr] ----
        f32x4 scB[4] = {}, scA[4] = {};
#pragma unroll
        for (int ks = 0; ks < 2; ++ks) {
            bf16x8 kf[4];
#pragma unroll
            for (int j = 0; j < 4; ++j)
                kf[j] = *(const bf16x8*)(Kc + (j * 16 + lr) * 64 + ((ks * 32 + lk * 8) ^ xoff));
            __builtin_amdgcn_s_setprio(1);
#pragma unroll
            for (int j = 0; j < 4; ++j)
                scB[j] = __builtin_amdgcn_mfma_f32_16x16x32_bf16(kf[j], qfB[ks], scB[j], 0, 0, 0);
            if (doA) {
#pragma unroll
                for (int j = 0; j < 4; ++j)
                    scA[j] = __builtin_amdgcn_mfma_f32_16x16x32_bf16(kf[j], qfA[ks], scA[j], 0, 0, 0);
            }
            __builtin_amdgcn_s_setprio(0);
        }

        // vf hoisted once per visit; loads overlap the softmax below
        bf16x8 vf[2][4];
#pragma unroll
        for (int ks = 0; ks < 2; ++ks)
#pragma unroll
            for (int j = 0; j < 4; ++j)
                vf[ks][j] = *(const bf16x8*)(Vc + (j * 16 + lr) * 64 + ((ks * 32 + lk * 8) ^ xoff));

        // ---- fixed-max softmax: P = exp2(sc - MFIX); branchless, lane-local ----
        auto smx = [&](f32x4* sc, float& ssum, int qX, bool diag, int st) {
            if (diag) {
#pragma unroll
                for (int j = 0; j < 4; ++j)
#pragma unroll
                    for (int r = 0; r < 4; ++r)
                        if (kv0 + j * 16 + lk * 4 + r > qX + lr) sc[j][r] = -1e30f;
            }
            float l0 = 0.f, l1 = 0.f, l2 = 0.f, l3 = 0.f;
#pragma unroll
            for (int j = 0; j < 4; ++j) {
                float pv[4];
                pv[0] = exp2f(sc[j][0] - MFIX);
                pv[1] = exp2f(sc[j][1] - MFIX);
                pv[2] = exp2f(sc[j][2] - MFIX);
                pv[3] = exp2f(sc[j][3] - MFIX);
                l0 += pv[0]; l1 += pv[1]; l2 += pv[2]; l3 += pv[3];
                union { bf16 h[4]; ushort4 s4; } u;
#pragma unroll
                for (int r = 0; r < 4; ++r) u.h[r] = __float2bfloat16(pv[r]);
                *(ushort4*)(&Pl[wave][st][lr][j * 16 + lk * 4]) = u.s4;
            }
            ssum += (l0 + l1) + (l2 + l3);
        };
        // ---- PV for strip st: o[j] (= O^T[d][q]) += mfma(vf, pf) ----
        auto pv = [&](f32x4* o, int st) {
#pragma unroll
            for (int ks = 0; ks < 2; ++ks) {
                const bf16x8 pf = *(const bf16x8*)(&Pl[wave][st][lr][ks * 32 + lk * 8]);
                __builtin_amdgcn_s_setprio(1);
#pragma unroll
                for (int j = 0; j < 4; ++j)
                    o[j] = __builtin_amdgcn_mfma_f32_16x16x32_bf16(vf[ks][j], pf, o[j], 0, 0, 0);
                __builtin_amdgcn_s_setprio(0);
            }
        };

        smx(scB, sB, qB, kt == tB, 1);
        if (doA) smx(scA, sA, qA, kt == tA, 0);
        pv(oB, 1);
        if (doA) pv(oA, 0);

        __builtin_amdgcn_sched_barrier(0);
        __builtin_amdgcn_s_barrier();   // all reads of buf c done before next stage overwrites
    }

    const int b = bh >> 4, h = bh & 15;
    auto epi = [&](float ssum, f32x4* o, int qX) {
        float s = ssum;
        s += __shfl_xor(s, 16);
        s += __shfl_xor(s, 32);
        const float inv = 1.0f / s;
        const int qq = qX + lr;
        bf16* dst = attnb + (size_t)(b * 2048 + qq) * 1024 + h * 64 + lk * 4;
#pragma unroll
        for (int j = 0; j < 4; ++j) {
            union { bf16 h4[4]; ushort4 s4; } u;
#pragma unroll
            for (int r = 0; r < 4; ++r) u.h4[r] = __float2bfloat16(o[j][r] * inv);
            *(ushort4*)(dst + j * 16) = u.s4;
        }
    };
    epi(sA, oA, qA);
    epi(sB, oB, qB);
#undef STAGE
}

// ---------------- launch ----------------
extern "C" void kernel_launch(void* const* d_in, const int* in_sizes, int n_in,
                              void* d_out, int out_size, void* d_ws, size_t ws_size,
                              hipStream_t stream)
{
    const float* x   = (const float*)d_in[0];
    const float* wq  = (const float*)d_in[1];
    const float* wk  = (const float*)d_in[2];
    const float* wv  = (const float*)d_in[3];
    const float* wo  = (const float*)d_in[4];
    const int*   pos = (const int*)d_in[5];
    const void* theta = d_in[6];

    char* ws = (char*)d_ws;
    bf16* xb    = (bf16*)(ws + OFF_XB);
    bf16* attnb = (bf16*)(ws + OFF_XB);    // reuse: xb consumed before attn writes
    bf16* wqkvb = (bf16*)(ws + OFF_WQKVB);
    bf16* wob   = (bf16*)(ws + OFF_WOB);
    bf16* qb    = (bf16*)(ws + OFF_QB);
    bf16* kb    = (bf16*)(ws + OFF_KB);
    bf16* vtb   = (bf16*)(ws + OFF_VTB);
    float* cst  = (float*)(ws + OFF_CS);
    float* snt  = (float*)(ws + OFF_SN);

    prep_kernel<<<dim3(4096, 6), 256, 0, stream>>>(x, wq, wk, wv, wo, xb, wqkvb, wob,
                                                   pos, theta, cst, snt);
    gemm_bt<0, 128><<<dim3(32, 24), 256, 0, stream>>>(xb, wqkvb, 1024, 3072, nullptr,
                                                      qb, kb, vtb, cst, snt);
    attn_kernel<<<dim3(16, 32), 256, 0, stream>>>(qb, kb, vtb, attnb);
    gemm_bt<1, 64><<<dim3(64, 8), 256, 0, stream>>>(attnb, wob, 1024, 1024, (float*)d_out,
                                                    nullptr, nullptr, nullptr, nullptr, nullptr);
}